// Round 3
// baseline (217.516 us; speedup 1.0000x reference)
//
#include <hip/hip_runtime.h>

// ScaledDotProductAttention: B=2,H=16,S=2048,DK=64, fp32 in/out, int mask (0/1).
// Strategy: f16 MFMA flash-attention.
//   prepass: Q,K->f16 ; V->V^T f16 ; mask->bitpack (ballot)
//   main:    swapped QK^T (S^T = K*Q^T) so softmax is lane-local per q-row;
//            PV as O^T = V^T * P^T; K/V^T staged via global_load_lds with
//            pre-swizzled source (XOR granule swizzle, m173 pattern).

#define S_   2048
#define D_   64
#define H_   16
#define B_   2
#define BH_  32
#define KVB  64
#define NKV  (S_/KVB)      // 32
#define QPB  128           // q rows per block
#define NQT  (S_/QPB)      // 16
#define NQS  2             // 16-row q subtiles per wave (wave = 32 q rows)

typedef __attribute__((ext_vector_type(8))) _Float16 f16x8;
typedef __attribute__((ext_vector_type(4))) _Float16 f16x4;
typedef __attribute__((ext_vector_type(4))) float    f32x4;

static __device__ __forceinline__ void async16(const void* g, void* l) {
  __builtin_amdgcn_global_load_lds(
      (const __attribute__((address_space(1))) void*)g,
      (__attribute__((address_space(3))) void*)l, 16, 0, 0);
}

// ---------------- prepass: fp32 -> f16 (vectorized) ----------------
__global__ __launch_bounds__(256) void cvt_f32_f16_k(
    const float* __restrict__ src, _Float16* __restrict__ dst, int n4) {
  int i = blockIdx.x * blockDim.x + threadIdx.x;
  int st = gridDim.x * blockDim.x;
  for (; i < n4; i += st) {
    float4 v = ((const float4*)src)[i];
    f16x4 o = {(_Float16)v.x, (_Float16)v.y, (_Float16)v.z, (_Float16)v.w};
    *(f16x4*)(dst + 4 * (size_t)i) = o;
  }
}

// ---------------- prepass: V[bh][s][d] fp32 -> V^T[bh][d][s] f16 ----------------
__global__ __launch_bounds__(256) void transpose_v_k(
    const float* __restrict__ V, _Float16* __restrict__ Vt) {
  __shared__ float tile[64][65];
  int bid = blockIdx.x;
  int st = bid & 31;          // s-tile (S/64 = 32)
  int bh = bid >> 5;
  const float* src = V + ((size_t)bh * S_ + st * 64) * D_;
  int r = threadIdx.x >> 2, cq = threadIdx.x & 3;
#pragma unroll
  for (int j = 0; j < 4; ++j) {
    float4 v = ((const float4*)(src + (size_t)r * D_))[cq + 4 * j];
    int col = (cq + 4 * j) * 4;
    tile[r][col + 0] = v.x; tile[r][col + 1] = v.y;
    tile[r][col + 2] = v.z; tile[r][col + 3] = v.w;
  }
  __syncthreads();
  int d = threadIdx.x >> 2, s = (threadIdx.x & 3) * 16;
  _Float16 tmp[16];
#pragma unroll
  for (int j = 0; j < 16; ++j) tmp[j] = (_Float16)tile[s + j][d];
  _Float16* dstp = Vt + ((size_t)bh * D_ + d) * S_ + st * 64 + s;
  *(f16x8*)(dstp)     = *((f16x8*)tmp);
  *(f16x8*)(dstp + 8) = *((f16x8*)tmp + 1);
}

// ---------------- prepass: mask int32 -> bitmask (bit i of word w == mask[w*64+i]!=0) ----
__global__ __launch_bounds__(256) void pack_mask_k(
    const int* __restrict__ mask, unsigned long long* __restrict__ bits, int nwords) {
  int lane = threadIdx.x & 63;
  int w0 = (blockIdx.x * blockDim.x + threadIdx.x) >> 6;
  int nw = (gridDim.x * blockDim.x) >> 6;
  for (int w = w0; w < nwords; w += nw) {
    int m = mask[(size_t)w * 64 + lane];
    unsigned long long bal = __ballot(m != 0);
    if (lane == 0) bits[w] = bal;
  }
}

// ---------------- main attention ----------------
__global__ __launch_bounds__(256) void attn_fwd(
    const _Float16* __restrict__ Qh, const _Float16* __restrict__ Kh,
    const _Float16* __restrict__ Vth, const unsigned long long* __restrict__ Mb,
    float* __restrict__ Out) {
  __shared__ _Float16 Kt[KVB * D_];        // [k_row][d], 16B granules XOR-swizzled by row&7
  __shared__ _Float16 Vt[D_ * KVB];        // [d][k],     16B granules XOR-swizzled by row&7
  __shared__ _Float16 Pl[4 * NQS][16 * KVB];  // per (wave,qs): [q_local][k], swizzled

  const int tid = threadIdx.x;
  const int lane = tid & 63;
  const int wid = tid >> 6;
  const int g = lane >> 4;
  const int c = lane & 15;
  const int c7 = c & 7;

  int bid = blockIdx.x;
  bid = (bid & 7) * 64 + (bid >> 3);       // XCD swizzle, bijective (512 = 8*64)
  const int qt = bid & (NQT - 1);
  const int bh = bid >> 4;
  const int b = bh >> 4;                   // bh = b*16 + h

  const int q0 = qt * QPB + wid * (NQS * 16);

  const _Float16* Kbh = Kh + (size_t)bh * S_ * D_;
  const _Float16* Vbh = Vth + (size_t)bh * D_ * S_;

  // Q fragments (B-operand of S^T = K*Q^T): lane holds Q[q0+qs*16+c][dc*32 + 8g + i]
  f16x8 qf[NQS][2];
#pragma unroll
  for (int qs = 0; qs < NQS; ++qs) {
    const _Float16* qp = Qh + ((size_t)bh * S_ + q0 + qs * 16 + c) * D_ + g * 8;
    qf[qs][0] = *(const f16x8*)(qp);
    qf[qs][1] = *(const f16x8*)(qp + 32);
  }

  f32x4 accO[NQS][4];
#pragma unroll
  for (int qs = 0; qs < NQS; ++qs)
#pragma unroll
    for (int dp = 0; dp < 4; ++dp) accO[qs][dp] = {0.f, 0.f, 0.f, 0.f};

  float m_run[NQS], l_run[NQS];
#pragma unroll
  for (int qs = 0; qs < NQS; ++qs) { m_run[qs] = -INFINITY; l_run[qs] = 0.f; }

  for (int kv = 0; kv < NKV; ++kv) {
    __syncthreads();
    // stage K tile [64][64] and V^T tile [64][64] (f16), source pre-swizzled so
    // LDS granule gr of row r holds global granule gr^(r&7).
#pragma unroll
    for (int it = 0; it < 2; ++it) {
      int idx = it * 256 + tid;
      int row = idx >> 3, gr = idx & 7;
      async16(Kbh + ((size_t)(kv * KVB + row)) * D_ + ((gr ^ (row & 7)) << 3),
              &Kt[(idx & ~63) * 8]);
      async16(Vbh + (size_t)row * S_ + kv * KVB + ((gr ^ (row & 7)) << 3),
              &Vt[(idx & ~63) * 8]);
    }
    __syncthreads();

    // K fragments (A-operand): lane holds K[kt*16+c][dc*32 + 8g + i]
    f16x8 kfr[4][2];
#pragma unroll
    for (int kt = 0; kt < 4; ++kt)
#pragma unroll
      for (int dc = 0; dc < 2; ++dc) {
        int row = kt * 16 + c;
        kfr[kt][dc] = *(const f16x8*)(&Kt[row * D_ + (((dc * 4 + g) ^ c7) << 3)]);
      }

    // S^T tiles: st[qs][kt][r] = S[q0+qs*16+c][kv*64 + kt*16 + 4g + r] (unscaled)
    f32x4 st[NQS][4];
#pragma unroll
    for (int qs = 0; qs < NQS; ++qs)
#pragma unroll
      for (int kt = 0; kt < 4; ++kt) {
        f32x4 a = {0.f, 0.f, 0.f, 0.f};
        a = __builtin_amdgcn_mfma_f32_16x16x32_f16(kfr[kt][0], qf[qs][0], a, 0, 0, 0);
        a = __builtin_amdgcn_mfma_f32_16x16x32_f16(kfr[kt][1], qf[qs][1], a, 0, 0, 0);
        st[qs][kt] = a;
      }

    // online softmax per q-row (lane-local thanks to swapped QK^T)
#pragma unroll
    for (int qs = 0; qs < NQS; ++qs) {
      unsigned long long mw = Mb[((size_t)b * S_ + q0 + qs * 16 + c) * NKV + kv];
      float s[16];
      float mx = -INFINITY;
#pragma unroll
      for (int kt = 0; kt < 4; ++kt)
#pragma unroll
        for (int r = 0; r < 4; ++r) {
          float v = st[qs][kt][r] * 0.125f;                 // 1/sqrt(64)
          int kl = kt * 16 + 4 * g + r;
          v = ((mw >> kl) & 1ull) ? v : -1.0e9f;
          s[kt * 4 + r] = v;
          mx = fmaxf(mx, v);
        }
      mx = fmaxf(mx, __shfl_xor(mx, 16));
      mx = fmaxf(mx, __shfl_xor(mx, 32));
      float mn = fmaxf(m_run[qs], mx);
      float rs = 0.f;
      f16x4 ph[4];
#pragma unroll
      for (int kt = 0; kt < 4; ++kt)
#pragma unroll
        for (int r = 0; r < 4; ++r) {
          float pe = __expf(s[kt * 4 + r] - mn);
          rs += pe;
          ph[kt][r] = (_Float16)pe;
        }
      rs += __shfl_xor(rs, 16);
      rs += __shfl_xor(rs, 32);
      float cf = __expf(m_run[qs] - mn);
      m_run[qs] = mn;
      l_run[qs] = l_run[qs] * cf + rs;
#pragma unroll
      for (int dp = 0; dp < 4; ++dp) accO[qs][dp] = accO[qs][dp] * cf;
      // write P (f16) into per-wave LDS, swizzled: k-granule Gk lives at Gk^(c&7)
      _Float16* pw = Pl[wid * NQS + qs] + c * KVB;
#pragma unroll
      for (int kt = 0; kt < 4; ++kt) {
        int gp = (2 * kt + (g >> 1)) ^ c7;
        *(f16x4*)(pw + gp * 8 + (g & 1) * 4) = ph[kt];
      }
    }
    asm volatile("s_waitcnt lgkmcnt(0)" ::: "memory");
    __builtin_amdgcn_sched_barrier(0);

    // PV: O^T = V^T * P^T, accumulate with rescaled accO
#pragma unroll
    for (int ks = 0; ks < 2; ++ks) {
      f16x8 vfr[4];
#pragma unroll
      for (int dp = 0; dp < 4; ++dp) {
        int row = dp * 16 + c;
        vfr[dp] = *(const f16x8*)(&Vt[row * KVB + (((4 * ks + g) ^ c7) << 3)]);
      }
#pragma unroll
      for (int qs = 0; qs < NQS; ++qs) {
        const _Float16* pr = Pl[wid * NQS + qs] + c * KVB + (((4 * ks + g) ^ c7) << 3);
        f16x8 pf = *(const f16x8*)pr;
#pragma unroll
        for (int dp = 0; dp < 4; ++dp)
          accO[qs][dp] = __builtin_amdgcn_mfma_f32_16x16x32_f16(vfr[dp], pf, accO[qs][dp], 0, 0, 0);
      }
    }
  }

  // epilogue: divide by softmax denom, store fp32
#pragma unroll
  for (int qs = 0; qs < NQS; ++qs) {
    float inv = 1.0f / l_run[qs];
    float* op = Out + ((size_t)bh * S_ + q0 + qs * 16 + c) * D_;
#pragma unroll
    for (int dp = 0; dp < 4; ++dp) {
      f32x4 o = accO[qs][dp] * inv;
      *(f32x4*)(op + dp * 16 + 4 * g) = o;
    }
  }
}

extern "C" void kernel_launch(void* const* d_in, const int* in_sizes, int n_in,
                              void* d_out, int out_size, void* d_ws, size_t ws_size,
                              hipStream_t stream) {
  const float* Q = (const float*)d_in[0];
  const float* K = (const float*)d_in[1];
  const float* V = (const float*)d_in[2];
  const int*   M = (const int*)d_in[3];
  float* Out = (float*)d_out;

  const size_t NE = (size_t)B_ * H_ * S_ * D_;   // 4194304
  _Float16* Qh  = (_Float16*)d_ws;               // 8 MB
  _Float16* Kh  = Qh + NE;                       // 8 MB
  _Float16* Vth = Kh + NE;                       // 8 MB (transposed)
  unsigned long long* Mb = (unsigned long long*)(Vth + NE);  // 1 MB

  cvt_f32_f16_k<<<1024, 256, 0, stream>>>(Q, Qh, (int)(NE / 4));
  cvt_f32_f16_k<<<1024, 256, 0, stream>>>(K, Kh, (int)(NE / 4));
  transpose_v_k<<<1024, 256, 0, stream>>>(V, Vth);
  pack_mask_k<<<1024, 256, 0, stream>>>(M, Mb, B_ * S_ * (S_ / 64));
  attn_fwd<<<NQT * BH_, 256, 0, stream>>>(Qh, Kh, Vth, Mb, Out);
}

// Round 5
// 201.577 us; speedup vs baseline: 1.0791x; 1.0791x over previous
//
#include <hip/hip_runtime.h>

// ScaledDotProductAttention: B=2,H=16,S=2048,DK=64, fp32 in/out, int mask (0/1).
// R5 = R4 with cvt_pkrtz type fix (bit_cast __fp16x2 -> _Float16x2).
// 8-wave blocks (occupancy 2x), thinned softmax (exp2 domain, post-exp
// LUT mask, pk cvt, fdot2 row-sum, defer-max), fused single prepass,
// Q converted in-kernel (block-private rows).

#define S_   2048
#define D_   64
#define H_   16
#define B_   2
#define BH_  32
#define KVB  64
#define NKV  (S_/KVB)      // 32
#define QPB  128           // q rows per block (8 waves x 16 rows)
#define NQT  (S_/QPB)      // 16

// softmax scale folded into K prepass, in log2 domain: 1/sqrt(64) * log2(e)
#define KSCALE 0.18033688f

typedef __attribute__((ext_vector_type(8))) _Float16 f16x8;
typedef __attribute__((ext_vector_type(4))) _Float16 f16x4;
typedef __attribute__((ext_vector_type(2))) _Float16 f16x2;
typedef __attribute__((ext_vector_type(4))) float    f32x4;

static __device__ __forceinline__ void async16(const void* g, void* l) {
  __builtin_amdgcn_global_load_lds(
      (const __attribute__((address_space(1))) void*)g,
      (__attribute__((address_space(3))) void*)l, 16, 0, 0);
}

static __device__ __forceinline__ f16x2 pkrtz(float a, float b) {
  return __builtin_bit_cast(f16x2, __builtin_amdgcn_cvt_pkrtz(a, b));
}

// ---------------- fused prepass ----------------
// blocks [0,1024): V[bh][s][d] f32 -> V^T[bh][d][s] f16
// blocks [1024,1536): K f32 -> f16, scaled by KSCALE
// blocks [1536,2048): mask int32 -> 64-bit bitmask words
__global__ __launch_bounds__(256) void prepass_k(
    const float* __restrict__ K, const float* __restrict__ V,
    const int* __restrict__ M,
    _Float16* __restrict__ Kh, _Float16* __restrict__ Vth,
    unsigned long long* __restrict__ Mb) {
  __shared__ float tile[64][65];
  const int bidx = blockIdx.x;
  const int tid = threadIdx.x;
  if (bidx < 1024) {
    // ---- V transpose ----
    int st = bidx & 31;          // s-tile
    int bh = bidx >> 5;
    const float* src = V + ((size_t)bh * S_ + st * 64) * D_;
    int r = tid >> 2, cq = tid & 3;
#pragma unroll
    for (int j = 0; j < 4; ++j) {
      float4 v = ((const float4*)(src + (size_t)r * D_))[cq + 4 * j];
      int col = (cq + 4 * j) * 4;
      tile[r][col + 0] = v.x; tile[r][col + 1] = v.y;
      tile[r][col + 2] = v.z; tile[r][col + 3] = v.w;
    }
    __syncthreads();
    int d = tid >> 2, s = (tid & 3) * 16;
    _Float16 tmp[16];
#pragma unroll
    for (int j = 0; j < 16; ++j) tmp[j] = (_Float16)tile[s + j][d];
    _Float16* dstp = Vth + ((size_t)bh * D_ + d) * S_ + st * 64 + s;
    *(f16x8*)(dstp)     = *((f16x8*)tmp);
    *(f16x8*)(dstp + 8) = *((f16x8*)tmp + 1);
  } else if (bidx < 1536) {
    // ---- K convert + scale ----
    int idx = (bidx - 1024) * 256 + tid;     // 0..131071
#pragma unroll
    for (int j = 0; j < 8; ++j) {
      int i = idx + j * 131072;              // < 1048576 float4s
      float4 v = ((const float4*)K)[i];
      f16x4 o = {(_Float16)(v.x * KSCALE), (_Float16)(v.y * KSCALE),
                 (_Float16)(v.z * KSCALE), (_Float16)(v.w * KSCALE)};
      *(f16x4*)(Kh + 4 * (size_t)i) = o;
    }
  } else {
    // ---- mask bitpack ----
    int lane = tid & 63;
    int wb = (bidx - 1536) * 256 + (tid >> 6) * 64;
    for (int i = 0; i < 64; ++i) {
      int w = wb + i;
      int m = M[(size_t)w * 64 + lane];
      unsigned long long bal = __ballot(m != 0);
      if (lane == 0) Mb[w] = bal;
    }
  }
}

// ---------------- main attention ----------------
__global__ __launch_bounds__(512, 4) void attn_fwd(
    const float* __restrict__ Qf, const _Float16* __restrict__ Kh,
    const _Float16* __restrict__ Vth, const unsigned long long* __restrict__ Mb,
    float* __restrict__ Out) {
  __shared__ _Float16 Kt[KVB * D_];          // 8KB  [k_row][d], granule-swizzled
  __shared__ _Float16 Vt[D_ * KVB];          // 8KB  [d][k],     granule-swizzled
  __shared__ _Float16 Pl[8][16 * KVB];       // 16KB per-wave P
  __shared__ unsigned long long MLUT[16];    // nibble -> f16x4 {0|1,...}

  const int tid = threadIdx.x;
  const int lane = tid & 63;
  const int wid = tid >> 6;                  // 0..7
  const int g = lane >> 4;
  const int c = lane & 15;
  const int c7 = c & 7;

  if (tid < 16) {
    unsigned w0 = ((tid & 1) ? 0x3C00u : 0u) | ((tid & 2) ? 0x3C000000u : 0u);
    unsigned w1 = ((tid & 4) ? 0x3C00u : 0u) | ((tid & 8) ? 0x3C000000u : 0u);
    MLUT[tid] = (unsigned long long)w0 | ((unsigned long long)w1 << 32);
  }

  int bid = blockIdx.x;
  bid = (bid & 7) * 64 + (bid >> 3);         // XCD swizzle, bijective (512 = 8*64)
  const int qt = bid & (NQT - 1);
  const int bh = bid >> 4;
  const int b = bh >> 4;                     // bh = b*16 + h

  const int q0 = qt * QPB + wid * 16;        // this wave's 16 q rows

  // ---- Q fragments straight from fp32 global (block-private rows) ----
  f16x8 qf[2];
  {
    const float* qp = Qf + ((size_t)bh * S_ + q0 + c) * D_ + 8 * g;
    _Float16 t[16];
#pragma unroll
    for (int j = 0; j < 8; ++j) t[j] = (_Float16)qp[j];
#pragma unroll
    for (int j = 0; j < 8; ++j) t[8 + j] = (_Float16)qp[32 + j];
    qf[0] = *(f16x8*)t;
    qf[1] = *((f16x8*)t + 1);
  }

  f32x4 accO[4];
#pragma unroll
  for (int dp = 0; dp < 4; ++dp) accO[dp] = {0.f, 0.f, 0.f, 0.f};
  float m_run = -INFINITY, l_run = 0.f;

  // staging pointers (source carries the XOR granule swizzle; LDS stays linear)
  const int srow = tid >> 3, sgr = tid & 7;
  const _Float16* kp = Kh + (size_t)bh * S_ * D_ + (size_t)srow * D_ + ((sgr ^ (srow & 7)) << 3);
  const _Float16* vp = Vth + (size_t)bh * D_ * S_ + (size_t)srow * S_ + ((sgr ^ (srow & 7)) << 3);
  _Float16* ldk = &Kt[(tid & ~63) * 8];      // wave-uniform base, lane*16B implicit
  _Float16* ldv = &Vt[(tid & ~63) * 8];
  const unsigned long long* pmb = Mb + ((size_t)b * S_ + q0 + c) * NKV;

  const f16x2 one2 = {(_Float16)1.0f, (_Float16)1.0f};

  for (int kv = 0; kv < NKV; ++kv) {
    __syncthreads();
    async16(kp, ldk);
    async16(vp, ldv);
    kp += KVB * D_;
    vp += KVB;
    unsigned long long mw = pmb[kv];         // overlap with staging drain
    __syncthreads();

    // ---- QK^T: S^T tiles, lane holds S[q0+c][kv*64 + kt*16 + 4g + r] ----
    f32x4 st[4];
#pragma unroll
    for (int kt = 0; kt < 4; ++kt) {
      int row = kt * 16 + c;
      f16x8 k0 = *(const f16x8*)(&Kt[row * D_ + (((0 * 4 + g) ^ c7) << 3)]);
      f16x8 k1 = *(const f16x8*)(&Kt[row * D_ + (((1 * 4 + g) ^ c7) << 3)]);
      f32x4 a = {0.f, 0.f, 0.f, 0.f};
      a = __builtin_amdgcn_mfma_f32_16x16x32_f16(k0, qf[0], a, 0, 0, 0);
      a = __builtin_amdgcn_mfma_f32_16x16x32_f16(k1, qf[1], a, 0, 0, 0);
      st[kt] = a;
    }

    // ---- online softmax (log2 domain; scale pre-folded into K) ----
    float pmax = st[0][0];
#pragma unroll
    for (int kt = 0; kt < 4; ++kt)
#pragma unroll
      for (int r = 0; r < 4; ++r) pmax = fmaxf(pmax, st[kt][r]);
    pmax = fmaxf(pmax, __shfl_xor(pmax, 16));
    pmax = fmaxf(pmax, __shfl_xor(pmax, 32));
    if (!__all(pmax - m_run <= 8.f)) {       // defer-max (T13): rescale rarely
      float mn = fmaxf(m_run, pmax);
      float cf = __builtin_amdgcn_exp2f(m_run - mn);
      l_run *= cf;
#pragma unroll
      for (int dp = 0; dp < 4; ++dp) accO[dp] = accO[dp] * cf;
      m_run = mn;
    }

    const unsigned mlo = (unsigned)mw, mhi = (unsigned)(mw >> 32);
    float rs = 0.f;
    f16x2 wv[8];
#pragma unroll
    for (int kt = 0; kt < 4; ++kt) {
      unsigned nib = (((kt < 2) ? mlo : mhi) >> (((kt & 1) << 4) + 4 * g)) & 0xFu;
      unsigned long long lut = MLUT[nib];
      f16x2 m01 = __builtin_bit_cast(f16x2, (unsigned)lut);
      f16x2 m23 = __builtin_bit_cast(f16x2, (unsigned)(lut >> 32));
      f16x2 p01 = pkrtz(__builtin_amdgcn_exp2f(st[kt][0] - m_run),
                        __builtin_amdgcn_exp2f(st[kt][1] - m_run));
      f16x2 p23 = pkrtz(__builtin_amdgcn_exp2f(st[kt][2] - m_run),
                        __builtin_amdgcn_exp2f(st[kt][3] - m_run));
      wv[2 * kt]     = p01 * m01;            // v_pk_mul_f16, mask post-exp
      wv[2 * kt + 1] = p23 * m23;
      rs = __builtin_amdgcn_fdot2(wv[2 * kt], one2, rs, false);
      rs = __builtin_amdgcn_fdot2(wv[2 * kt + 1], one2, rs, false);
    }
    rs += __shfl_xor(rs, 16);
    rs += __shfl_xor(rs, 32);
    l_run += rs;

    // ---- write P to per-wave LDS (granule-swizzled, layout as R3) ----
    _Float16* pw = Pl[wid] + c * KVB;
#pragma unroll
    for (int kt = 0; kt < 4; ++kt) {
      int gp = (2 * kt + (g >> 1)) ^ c7;
      uint2 wpair = {__builtin_bit_cast(unsigned, wv[2 * kt]),
                     __builtin_bit_cast(unsigned, wv[2 * kt + 1])};
      *(uint2*)(pw + gp * 8 + (g & 1) * 4) = wpair;
    }
    asm volatile("s_waitcnt lgkmcnt(0)" ::: "memory");
    __builtin_amdgcn_sched_barrier(0);

    // ---- PV: O^T = V^T * P^T ----
#pragma unroll
    for (int ks = 0; ks < 2; ++ks) {
      const _Float16* pr = Pl[wid] + c * KVB + (((4 * ks + g) ^ c7) << 3);
      f16x8 pf = *(const f16x8*)pr;
#pragma unroll
      for (int dp = 0; dp < 4; ++dp) {
        int row = dp * 16 + c;
        f16x8 vfr = *(const f16x8*)(&Vt[row * KVB + (((4 * ks + g) ^ c7) << 3)]);
        accO[dp] = __builtin_amdgcn_mfma_f32_16x16x32_f16(vfr, pf, accO[dp], 0, 0, 0);
      }
    }
  }

  // ---- epilogue ----
  float inv = 1.0f / l_run;
  float* op = Out + ((size_t)bh * S_ + q0 + c) * D_;
#pragma unroll
  for (int dp = 0; dp < 4; ++dp) {
    f32x4 o = accO[dp] * inv;
    *(f32x4*)(op + dp * 16 + 4 * g) = o;
  }
}

extern "C" void kernel_launch(void* const* d_in, const int* in_sizes, int n_in,
                              void* d_out, int out_size, void* d_ws, size_t ws_size,
                              hipStream_t stream) {
  const float* Q = (const float*)d_in[0];
  const float* K = (const float*)d_in[1];
  const float* V = (const float*)d_in[2];
  const int*   M = (const int*)d_in[3];
  float* Out = (float*)d_out;

  const size_t NE = (size_t)B_ * H_ * S_ * D_;            // 4194304
  _Float16* Kh  = (_Float16*)d_ws;                        // 8 MB
  _Float16* Vth = Kh + NE;                                // 8 MB (transposed)
  unsigned long long* Mb = (unsigned long long*)(Vth + NE); // 1 MB

  prepass_k<<<2048, 256, 0, stream>>>(K, V, M, Kh, Vth, Mb);
  attn_fwd<<<NQT * BH_, 512, 0, stream>>>(Q, Kh, Vth, Mb, Out);
}

// Round 6
// 194.982 us; speedup vs baseline: 1.1156x; 1.0338x over previous
//
#include <hip/hip_runtime.h>

// ScaledDotProductAttention: B=2,H=16,S=2048,DK=64, fp32 in/out, int mask (0/1).
// R6 = R5 + double-buffered K/V staging with single barrier per kv-tile
// (T3-minimum pipeline: __syncthreads' implicit vmcnt drain is the wait for
// the tile staged during the PREVIOUS iteration), 3 blocks/CU, setprio (T5).

#define S_   2048
#define D_   64
#define H_   16
#define B_   2
#define BH_  32
#define KVB  64
#define NKV  (S_/KVB)      // 32
#define QPB  128           // q rows per block (8 waves x 16 rows)
#define NQT  (S_/QPB)      // 16

// softmax scale folded into K prepass, in log2 domain: 1/sqrt(64) * log2(e)
#define KSCALE 0.18033688f

typedef __attribute__((ext_vector_type(8))) _Float16 f16x8;
typedef __attribute__((ext_vector_type(4))) _Float16 f16x4;
typedef __attribute__((ext_vector_type(2))) _Float16 f16x2;
typedef __attribute__((ext_vector_type(4))) float    f32x4;

static __device__ __forceinline__ void async16(const void* g, void* l) {
  __builtin_amdgcn_global_load_lds(
      (const __attribute__((address_space(1))) void*)g,
      (__attribute__((address_space(3))) void*)l, 16, 0, 0);
}

static __device__ __forceinline__ f16x2 pkrtz(float a, float b) {
  return __builtin_bit_cast(f16x2, __builtin_amdgcn_cvt_pkrtz(a, b));
}

// ---------------- fused prepass ----------------
// blocks [0,1024): V[bh][s][d] f32 -> V^T[bh][d][s] f16
// blocks [1024,1536): K f32 -> f16, scaled by KSCALE
// blocks [1536,2048): mask int32 -> 64-bit bitmask words
__global__ __launch_bounds__(256) void prepass_k(
    const float* __restrict__ K, const float* __restrict__ V,
    const int* __restrict__ M,
    _Float16* __restrict__ Kh, _Float16* __restrict__ Vth,
    unsigned long long* __restrict__ Mb) {
  __shared__ float tile[64][65];
  const int bidx = blockIdx.x;
  const int tid = threadIdx.x;
  if (bidx < 1024) {
    // ---- V transpose ----
    int st = bidx & 31;          // s-tile
    int bh = bidx >> 5;
    const float* src = V + ((size_t)bh * S_ + st * 64) * D_;
    int r = tid >> 2, cq = tid & 3;
#pragma unroll
    for (int j = 0; j < 4; ++j) {
      float4 v = ((const float4*)(src + (size_t)r * D_))[cq + 4 * j];
      int col = (cq + 4 * j) * 4;
      tile[r][col + 0] = v.x; tile[r][col + 1] = v.y;
      tile[r][col + 2] = v.z; tile[r][col + 3] = v.w;
    }
    __syncthreads();
    int d = tid >> 2, s = (tid & 3) * 16;
    _Float16 tmp[16];
#pragma unroll
    for (int j = 0; j < 16; ++j) tmp[j] = (_Float16)tile[s + j][d];
    _Float16* dstp = Vth + ((size_t)bh * D_ + d) * S_ + st * 64 + s;
    *(f16x8*)(dstp)     = *((f16x8*)tmp);
    *(f16x8*)(dstp + 8) = *((f16x8*)tmp + 1);
  } else if (bidx < 1536) {
    // ---- K convert + scale ----
    int idx = (bidx - 1024) * 256 + tid;     // 0..131071
#pragma unroll
    for (int j = 0; j < 8; ++j) {
      int i = idx + j * 131072;              // < 1048576 float4s
      float4 v = ((const float4*)K)[i];
      f16x4 o = {(_Float16)(v.x * KSCALE), (_Float16)(v.y * KSCALE),
                 (_Float16)(v.z * KSCALE), (_Float16)(v.w * KSCALE)};
      *(f16x4*)(Kh + 4 * (size_t)i) = o;
    }
  } else {
    // ---- mask bitpack ----
    int lane = tid & 63;
    int wb = (bidx - 1536) * 256 + (tid >> 6) * 64;
    for (int i = 0; i < 64; ++i) {
      int w = wb + i;
      int m = M[(size_t)w * 64 + lane];
      unsigned long long bal = __ballot(m != 0);
      if (lane == 0) Mb[w] = bal;
    }
  }
}

// ---------------- main attention ----------------
__global__ __launch_bounds__(512, 6) void attn_fwd(
    const float* __restrict__ Qf, const _Float16* __restrict__ Kh,
    const _Float16* __restrict__ Vth, const unsigned long long* __restrict__ Mb,
    float* __restrict__ Out) {
  __shared__ _Float16 Kt[2][KVB * D_];       // 16KB double-buffered [k_row][d]
  __shared__ _Float16 Vt[2][D_ * KVB];       // 16KB double-buffered [d][k]
  __shared__ _Float16 Pl[8][16 * KVB];       // 16KB per-wave P
  __shared__ unsigned long long MLUT[16];    // nibble -> f16x4 {0|1,...}

  const int tid = threadIdx.x;
  const int lane = tid & 63;
  const int wid = tid >> 6;                  // 0..7
  const int g = lane >> 4;
  const int c = lane & 15;
  const int c7 = c & 7;

  if (tid < 16) {
    unsigned w0 = ((tid & 1) ? 0x3C00u : 0u) | ((tid & 2) ? 0x3C000000u : 0u);
    unsigned w1 = ((tid & 4) ? 0x3C00u : 0u) | ((tid & 8) ? 0x3C000000u : 0u);
    MLUT[tid] = (unsigned long long)w0 | ((unsigned long long)w1 << 32);
  }

  int bid = blockIdx.x;
  bid = (bid & 7) * 64 + (bid >> 3);         // XCD swizzle, bijective (512 = 8*64)
  const int qt = bid & (NQT - 1);
  const int bh = bid >> 4;
  const int b = bh >> 4;                     // bh = b*16 + h

  const int q0 = qt * QPB + wid * 16;        // this wave's 16 q rows

  // ---- Q fragments straight from fp32 global (block-private rows) ----
  f16x8 qf[2];
  {
    const float* qp = Qf + ((size_t)bh * S_ + q0 + c) * D_ + 8 * g;
    _Float16 t[16];
#pragma unroll
    for (int j = 0; j < 8; ++j) t[j] = (_Float16)qp[j];
#pragma unroll
    for (int j = 0; j < 8; ++j) t[8 + j] = (_Float16)qp[32 + j];
    qf[0] = *(f16x8*)t;
    qf[1] = *((f16x8*)t + 1);
  }

  f32x4 accO[4];
#pragma unroll
  for (int dp = 0; dp < 4; ++dp) accO[dp] = {0.f, 0.f, 0.f, 0.f};
  float m_run = -INFINITY, l_run = 0.f;

  // staging pointers (source carries the XOR granule swizzle; LDS stays linear)
  const int srow = tid >> 3, sgr = tid & 7;
  const _Float16* kp0 = Kh + (size_t)bh * S_ * D_ + (size_t)srow * D_ + ((sgr ^ (srow & 7)) << 3);
  const _Float16* vp0 = Vth + (size_t)bh * D_ * S_ + (size_t)srow * S_ + ((sgr ^ (srow & 7)) << 3);
  _Float16* ldk = &Kt[0][(tid & ~63) * 8];   // wave-uniform base, lane*16B implicit
  _Float16* ldv = &Vt[0][(tid & ~63) * 8];
  const unsigned long long* pmb = Mb + ((size_t)b * S_ + q0 + c) * NKV;

  const f16x2 one2 = {(_Float16)1.0f, (_Float16)1.0f};

  // ---- prologue: stage tile 0 into buffer 0 (issue only; wait happens at
  // the loop-top __syncthreads, whose implicit vmcnt(0) drain is the sync) ----
  async16(kp0, ldk);
  async16(vp0, ldv);

#pragma unroll 2
  for (int kv = 0; kv < NKV; ++kv) {
    const int cur = kv & 1;
    __syncthreads();                         // buf[cur] staged by ALL waves

    // mask word for THIS tile: issue BEFORE the next-tile stage loads so the
    // compiler can wait it with a counted vmcnt (stage loads stay in flight)
    unsigned long long mw = pmb[kv];

    if (kv + 1 < NKV) {                      // issue next-tile stage, no wait
      const int nxt = cur ^ 1;
      async16(kp0 + (size_t)(kv + 1) * (KVB * D_), ldk + nxt * (KVB * D_));
      async16(vp0 + (size_t)(kv + 1) * KVB,        ldv + nxt * (D_ * KVB));
    }

    const _Float16* Ktc = Kt[cur];
    const _Float16* Vtc = Vt[cur];

    // ---- QK^T: S^T tiles, lane holds S[q0+c][kv*64 + kt*16 + 4g + r] ----
    f32x4 st[4];
    __builtin_amdgcn_s_setprio(1);
#pragma unroll
    for (int kt = 0; kt < 4; ++kt) {
      int row = kt * 16 + c;
      f16x8 k0 = *(const f16x8*)(&Ktc[row * D_ + (((0 * 4 + g) ^ c7) << 3)]);
      f16x8 k1 = *(const f16x8*)(&Ktc[row * D_ + (((1 * 4 + g) ^ c7) << 3)]);
      f32x4 a = {0.f, 0.f, 0.f, 0.f};
      a = __builtin_amdgcn_mfma_f32_16x16x32_f16(k0, qf[0], a, 0, 0, 0);
      a = __builtin_amdgcn_mfma_f32_16x16x32_f16(k1, qf[1], a, 0, 0, 0);
      st[kt] = a;
    }
    __builtin_amdgcn_s_setprio(0);

    // ---- online softmax (log2 domain; scale pre-folded into K) ----
    float pmax = st[0][0];
#pragma unroll
    for (int kt = 0; kt < 4; ++kt)
#pragma unroll
      for (int r = 0; r < 4; ++r) pmax = fmaxf(pmax, st[kt][r]);
    pmax = fmaxf(pmax, __shfl_xor(pmax, 16));
    pmax = fmaxf(pmax, __shfl_xor(pmax, 32));
    if (!__all(pmax - m_run <= 8.f)) {       // defer-max (T13): rescale rarely
      float mn = fmaxf(m_run, pmax);
      float cf = __builtin_amdgcn_exp2f(m_run - mn);
      l_run *= cf;
#pragma unroll
      for (int dp = 0; dp < 4; ++dp) accO[dp] = accO[dp] * cf;
      m_run = mn;
    }

    const unsigned mlo = (unsigned)mw, mhi = (unsigned)(mw >> 32);
    float rs = 0.f;
    f16x2 wv[8];
#pragma unroll
    for (int kt = 0; kt < 4; ++kt) {
      unsigned nib = (((kt < 2) ? mlo : mhi) >> (((kt & 1) << 4) + 4 * g)) & 0xFu;
      unsigned long long lut = MLUT[nib];
      f16x2 m01 = __builtin_bit_cast(f16x2, (unsigned)lut);
      f16x2 m23 = __builtin_bit_cast(f16x2, (unsigned)(lut >> 32));
      f16x2 p01 = pkrtz(__builtin_amdgcn_exp2f(st[kt][0] - m_run),
                        __builtin_amdgcn_exp2f(st[kt][1] - m_run));
      f16x2 p23 = pkrtz(__builtin_amdgcn_exp2f(st[kt][2] - m_run),
                        __builtin_amdgcn_exp2f(st[kt][3] - m_run));
      wv[2 * kt]     = p01 * m01;            // v_pk_mul_f16, mask post-exp
      wv[2 * kt + 1] = p23 * m23;
      rs = __builtin_amdgcn_fdot2(wv[2 * kt], one2, rs, false);
      rs = __builtin_amdgcn_fdot2(wv[2 * kt + 1], one2, rs, false);
    }
    rs += __shfl_xor(rs, 16);
    rs += __shfl_xor(rs, 32);
    l_run += rs;

    // ---- write P to per-wave LDS (granule-swizzled) ----
    _Float16* pw = Pl[wid] + c * KVB;
#pragma unroll
    for (int kt = 0; kt < 4; ++kt) {
      int gp = (2 * kt + (g >> 1)) ^ c7;
      uint2 wpair = {__builtin_bit_cast(unsigned, wv[2 * kt]),
                     __builtin_bit_cast(unsigned, wv[2 * kt + 1])};
      *(uint2*)(pw + gp * 8 + (g & 1) * 4) = wpair;
    }
    asm volatile("s_waitcnt lgkmcnt(0)" ::: "memory");
    __builtin_amdgcn_sched_barrier(0);

    // ---- PV: O^T = V^T * P^T ----
    __builtin_amdgcn_s_setprio(1);
#pragma unroll
    for (int ks = 0; ks < 2; ++ks) {
      const _Float16* pr = Pl[wid] + c * KVB + (((4 * ks + g) ^ c7) << 3);
      f16x8 pf = *(const f16x8*)pr;
#pragma unroll
      for (int dp = 0; dp < 4; ++dp) {
        int row = dp * 16 + c;
        f16x8 vfr = *(const f16x8*)(&Vtc[row * KVB + (((4 * ks + g) ^ c7) << 3)]);
        accO[dp] = __builtin_amdgcn_mfma_f32_16x16x32_f16(vfr, pf, accO[dp], 0, 0, 0);
      }
    }
    __builtin_amdgcn_s_setprio(0);
  }

  // ---- epilogue ----
  float inv = 1.0f / l_run;
  float* op = Out + ((size_t)bh * S_ + q0 + c) * D_;
#pragma unroll
  for (int dp = 0; dp < 4; ++dp) {
    f32x4 o = accO[dp] * inv;
    *(f32x4*)(op + dp * 16 + 4 * g) = o;
  }
}

extern "C" void kernel_launch(void* const* d_in, const int* in_sizes, int n_in,
                              void* d_out, int out_size, void* d_ws, size_t ws_size,
                              hipStream_t stream) {
  const float* Q = (const float*)d_in[0];
  const float* K = (const float*)d_in[1];
  const float* V = (const float*)d_in[2];
  const int*   M = (const int*)d_in[3];
  float* Out = (float*)d_out;

  const size_t NE = (size_t)B_ * H_ * S_ * D_;            // 4194304
  _Float16* Kh  = (_Float16*)d_ws;                        // 8 MB
  _Float16* Vth = Kh + NE;                                // 8 MB (transposed)
  unsigned long long* Mb = (unsigned long long*)(Vth + NE); // 1 MB

  prepass_k<<<2048, 256, 0, stream>>>(K, V, M, Kh, Vth, Mb);
  attn_fwd<<<NQT * BH_, 512, 0, stream>>>(Q, Kh, Vth, Mb, Out);
}

// Round 7
// 192.644 us; speedup vs baseline: 1.1291x; 1.0121x over previous
//
#include <hip/hip_runtime.h>

// ScaledDotProductAttention: B=2,H=16,S=2048,DK=64, fp32 in/out, int mask (0/1).
// R7: 32x32x16 MFMA structure, fully in-register P via cvt_pkrtz +
// permlane32_swap (T12) -- no P LDS, no lgkmcnt drain. 4 waves x 32 q-rows.
// Keeps: dbuf async staging (T3-min), defer-max (T13), LUT mask, exp2 domain.

#define S_   2048
#define D_   64
#define H_   16
#define B_   2
#define BH_  32
#define KVB  64
#define NKV  (S_/KVB)      // 32
#define QPB  128           // 4 waves x 32 q rows
#define NQT  (S_/QPB)      // 16

// softmax scale folded into K prepass, in log2 domain: 1/sqrt(64) * log2(e)
#define KSCALE 0.18033688f

typedef __attribute__((ext_vector_type(8)))  _Float16 f16x8;
typedef __attribute__((ext_vector_type(4)))  _Float16 f16x4;
typedef __attribute__((ext_vector_type(2)))  _Float16 f16x2;
typedef __attribute__((ext_vector_type(4)))  float    f32x4;
typedef __attribute__((ext_vector_type(16))) float    f32x16;
typedef __attribute__((ext_vector_type(4)))  unsigned u32x4;

static __device__ __forceinline__ void async16(const void* g, void* l) {
  __builtin_amdgcn_global_load_lds(
      (const __attribute__((address_space(1))) void*)g,
      (__attribute__((address_space(3))) void*)l, 16, 0, 0);
}

static __device__ __forceinline__ f16x2 pkrtz(float a, float b) {
  return __builtin_bit_cast(f16x2, __builtin_amdgcn_cvt_pkrtz(a, b));
}

// exchange: a<->b across wave halves. After call:
//   a: lanes<32 keep own a, lanes>=32 get partner's b
//   b: lanes<32 get partner's a, lanes>=32 keep own b
static __device__ __forceinline__ void plswap(unsigned& a, unsigned& b, int h) {
#if __has_builtin(__builtin_amdgcn_permlane32_swap)
  auto r = __builtin_amdgcn_permlane32_swap(a, b, false, false);
  a = (unsigned)r[0];
  b = (unsigned)r[1];
#else
  unsigned sa = __shfl_xor(a, 32), sb = __shfl_xor(b, 32);
  unsigned na = h ? sb : a, nb = h ? b : sa;
  a = na; b = nb;
#endif
}

// ---------------- fused prepass (unchanged from R6) ----------------
__global__ __launch_bounds__(256) void prepass_k(
    const float* __restrict__ K, const float* __restrict__ V,
    const int* __restrict__ M,
    _Float16* __restrict__ Kh, _Float16* __restrict__ Vth,
    unsigned long long* __restrict__ Mb) {
  __shared__ float tile[64][65];
  const int bidx = blockIdx.x;
  const int tid = threadIdx.x;
  if (bidx < 1024) {
    int st = bidx & 31;
    int bh = bidx >> 5;
    const float* src = V + ((size_t)bh * S_ + st * 64) * D_;
    int r = tid >> 2, cq = tid & 3;
#pragma unroll
    for (int j = 0; j < 4; ++j) {
      float4 v = ((const float4*)(src + (size_t)r * D_))[cq + 4 * j];
      int col = (cq + 4 * j) * 4;
      tile[r][col + 0] = v.x; tile[r][col + 1] = v.y;
      tile[r][col + 2] = v.z; tile[r][col + 3] = v.w;
    }
    __syncthreads();
    int d = tid >> 2, s = (tid & 3) * 16;
    _Float16 tmp[16];
#pragma unroll
    for (int j = 0; j < 16; ++j) tmp[j] = (_Float16)tile[s + j][d];
    _Float16* dstp = Vth + ((size_t)bh * D_ + d) * S_ + st * 64 + s;
    *(f16x8*)(dstp)     = *((f16x8*)tmp);
    *(f16x8*)(dstp + 8) = *((f16x8*)tmp + 1);
  } else if (bidx < 1536) {
    int idx = (bidx - 1024) * 256 + tid;
#pragma unroll
    for (int j = 0; j < 8; ++j) {
      int i = idx + j * 131072;
      float4 v = ((const float4*)K)[i];
      f16x4 o = {(_Float16)(v.x * KSCALE), (_Float16)(v.y * KSCALE),
                 (_Float16)(v.z * KSCALE), (_Float16)(v.w * KSCALE)};
      *(f16x4*)(Kh + 4 * (size_t)i) = o;
    }
  } else {
    int lane = tid & 63;
    int wb = (bidx - 1536) * 256 + (tid >> 6) * 64;
    for (int i = 0; i < 64; ++i) {
      int w = wb + i;
      int m = M[(size_t)w * 64 + lane];
      unsigned long long bal = __ballot(m != 0);
      if (lane == 0) Mb[w] = bal;
    }
  }
}

// ---------------- main attention ----------------
__global__ __launch_bounds__(256, 2) void attn_fwd(
    const float* __restrict__ Qf, const _Float16* __restrict__ Kh,
    const _Float16* __restrict__ Vth, const unsigned long long* __restrict__ Mb,
    float* __restrict__ Out) {
  __shared__ _Float16 Kt[2][KVB * D_];       // 16KB dbuf [k_row][d], granule-swizzled
  __shared__ _Float16 Vt[2][D_ * KVB];       // 16KB dbuf [d][k],     granule-swizzled
  __shared__ unsigned long long MLUT[16];

  const int tid = threadIdx.x;
  const int lane = tid & 63;
  const int wid = tid >> 6;                  // 0..3
  const int h = lane >> 5;                   // wave half
  const int c5 = lane & 31;
  const int c7 = c5 & 7;

  if (tid < 16) {
    unsigned w0 = ((tid & 1) ? 0x3C00u : 0u) | ((tid & 2) ? 0x3C000000u : 0u);
    unsigned w1 = ((tid & 4) ? 0x3C00u : 0u) | ((tid & 8) ? 0x3C000000u : 0u);
    MLUT[tid] = (unsigned long long)w0 | ((unsigned long long)w1 << 32);
  }

  int bid = blockIdx.x;
  bid = (bid & 7) * 64 + (bid >> 3);         // XCD swizzle, bijective (512 = 8*64)
  const int qt = bid & (NQT - 1);
  const int bh = bid >> 4;
  const int b = bh >> 4;                     // bh = b*16 + h

  const int q = qt * QPB + wid * 32 + c5;    // this lane's q row

  // ---- Q fragments from fp32 global: qf[dc] = Q[q][16dc+8h .. +8) ----
  f16x8 qf[4];
  {
    const float* qp = Qf + ((size_t)bh * S_ + q) * D_ + 8 * h;
#pragma unroll
    for (int dc = 0; dc < 4; ++dc) {
      _Float16 t[8];
#pragma unroll
      for (int j = 0; j < 8; ++j) t[j] = (_Float16)qp[16 * dc + j];
      qf[dc] = *(f16x8*)t;
    }
  }

  f32x16 accO0, accO1;
#pragma unroll
  for (int e = 0; e < 16; ++e) { accO0[e] = 0.f; accO1[e] = 0.f; }
  float m_run = -INFINITY, l_run = 0.f;

  const _Float16* kbase = Kh + (size_t)bh * S_ * D_;   // [s][d]
  const _Float16* vbase = Vth + (size_t)bh * D_ * S_;  // [d][s]
  const unsigned long long* pmb = Mb + ((size_t)b * S_ + q) * NKV;
  const f16x2 one2 = {(_Float16)1.0f, (_Float16)1.0f};

#define STAGE(buf, kvi)                                                     \
  {                                                                         \
    _Pragma("unroll") for (int it = 0; it < 2; ++it) {                      \
      int gid = it * 256 + tid;                                             \
      int row = gid >> 3, gr = gid & 7;                                     \
      int gs = (gr ^ (row & 7)) << 3;                                       \
      int ldso = ((gid & ~63) * 8);                                         \
      async16(kbase + ((size_t)((kvi)*KVB + row)) * D_ + gs, &Kt[buf][ldso]); \
      async16(vbase + (size_t)row * S_ + (kvi)*KVB + gs, &Vt[buf][ldso]);   \
    }                                                                       \
  }

  STAGE(0, 0);                               // prologue; wait = loop-top barrier

#pragma unroll 2
  for (int kv = 0; kv < NKV; ++kv) {
    const int cur = kv & 1;
    __syncthreads();                         // buf[cur] complete for all waves
    unsigned long long mw = pmb[kv];
    if (kv + 1 < NKV) STAGE(cur ^ 1, kv + 1);

    const _Float16* Ktc = Kt[cur];
    const _Float16* Vtc = Vt[cur];

    // ---- QK^T: S^T = K*Q^T in two 32x32 tiles (kt=0,1), chained over d ----
    f32x16 st0, st1;
#pragma unroll
    for (int e = 0; e < 16; ++e) { st0[e] = 0.f; st1[e] = 0.f; }
    __builtin_amdgcn_s_setprio(1);
#pragma unroll
    for (int dc = 0; dc < 4; ++dc) {
      int slot = (((2 * dc + h) ^ c7) << 3);
      f16x8 k0 = *(const f16x8*)(&Ktc[(c5)      * D_ + slot]);
      f16x8 k1 = *(const f16x8*)(&Ktc[(32 + c5) * D_ + slot]);
      st0 = __builtin_amdgcn_mfma_f32_32x32x16_f16(k0, qf[dc], st0, 0, 0, 0);
      st1 = __builtin_amdgcn_mfma_f32_32x32x16_f16(k1, qf[dc], st1, 0, 0, 0);
    }
    __builtin_amdgcn_s_setprio(0);
    // lane (h,c5) holds S[q][k = kt*32 + (e&3) + 8*(e>>2) + 4h], col q = c5

    // ---- online softmax (exp2 domain), row spans lanes {c5, c5+32} ----
    float pmax = -INFINITY;
#pragma unroll
    for (int e = 0; e < 16; ++e) {
      pmax = fmaxf(pmax, st0[e]);
      pmax = fmaxf(pmax, st1[e]);
    }
    pmax = fmaxf(pmax, __shfl_xor(pmax, 32));
    if (!__all(pmax - m_run <= 8.f)) {       // defer-max (T13)
      float mn = fmaxf(m_run, pmax);
      float cf = __builtin_amdgcn_exp2f(m_run - mn);
      l_run *= cf;
#pragma unroll
      for (int e = 0; e < 16; ++e) { accO0[e] *= cf; accO1[e] *= cf; }
      m_run = mn;
    }

    // ---- exp2 + mask (post-exp LUT) + f16 pack + row-sum ----
    // held chunk (kt,rr) = k [kt*32+8rr+4h, +4) = global nibble n = 8kt+2rr+h
    float rs = 0.f;
    unsigned pkd[2][4][2];
#pragma unroll
    for (int kt = 0; kt < 2; ++kt) {
#pragma unroll
      for (int rr = 0; rr < 4; ++rr) {
        int n = 8 * kt + 2 * rr + h;
        unsigned nib = (unsigned)(mw >> (4 * n)) & 0xFu;
        unsigned long long lut = MLUT[nib];
        f16x2 m01 = __builtin_bit_cast(f16x2, (unsigned)lut);
        f16x2 m23 = __builtin_bit_cast(f16x2, (unsigned)(lut >> 32));
        float e0 = (kt ? st1[4 * rr + 0] : st0[4 * rr + 0]) - m_run;
        float e1 = (kt ? st1[4 * rr + 1] : st0[4 * rr + 1]) - m_run;
        float e2 = (kt ? st1[4 * rr + 2] : st0[4 * rr + 2]) - m_run;
        float e3 = (kt ? st1[4 * rr + 3] : st0[4 * rr + 3]) - m_run;
        f16x2 p0 = pkrtz(__builtin_amdgcn_exp2f(e0), __builtin_amdgcn_exp2f(e1)) * m01;
        f16x2 p1 = pkrtz(__builtin_amdgcn_exp2f(e2), __builtin_amdgcn_exp2f(e3)) * m23;
        rs = __builtin_amdgcn_fdot2(p0, one2, rs, false);
        rs = __builtin_amdgcn_fdot2(p1, one2, rs, false);
        pkd[kt][rr][0] = __builtin_bit_cast(unsigned, p0);
        pkd[kt][rr][1] = __builtin_bit_cast(unsigned, p1);
      }
    }
    rs += __shfl_xor(rs, 32);
    l_run += rs;

    // ---- P redistribution: half-wave chunk exchange -> B-operand frags ----
    // held[j] = chunk 2j+h (j = 4kt+rr); frag kc needs chunks {4kc+2h, 4kc+2h+1}
    f16x8 pfrag[4];
#pragma unroll
    for (int kc = 0; kc < 4; ++kc) {
      int jl = 2 * kc, jh = 2 * kc + 1;
      unsigned a0 = pkd[jl >> 2][jl & 3][0], a1 = pkd[jl >> 2][jl & 3][1];
      unsigned b0 = pkd[jh >> 2][jh & 3][0], b1 = pkd[jh >> 2][jh & 3][1];
      plswap(a0, b0, h);
      plswap(a1, b1, h);
      u32x4 fr = {a0, a1, b0, b1};           // k ascending: 16kc+8h .. +8
      pfrag[kc] = __builtin_bit_cast(f16x8, fr);
    }

    // ---- PV: O^T = V^T * P^T, two d-tiles, chained over k ----
    __builtin_amdgcn_s_setprio(1);
#pragma unroll
    for (int kc = 0; kc < 4; ++kc) {
      int slot = (((2 * kc + h) ^ c7) << 3);
      f16x8 v0 = *(const f16x8*)(&Vtc[(c5)      * KVB + slot]);
      f16x8 v1 = *(const f16x8*)(&Vtc[(32 + c5) * KVB + slot]);
      accO0 = __builtin_amdgcn_mfma_f32_32x32x16_f16(v0, pfrag[kc], accO0, 0, 0, 0);
      accO1 = __builtin_amdgcn_mfma_f32_32x32x16_f16(v1, pfrag[kc], accO1, 0, 0, 0);
    }
    __builtin_amdgcn_s_setprio(0);
  }

  // ---- epilogue: O[q][d] = accO^T / l ----
  float inv = 1.0f / l_run;
  float* op = Out + ((size_t)bh * S_ + q) * D_;
#pragma unroll
  for (int rr = 0; rr < 4; ++rr) {
    f32x4 o0, o1;
#pragma unroll
    for (int e = 0; e < 4; ++e) {
      o0[e] = accO0[4 * rr + e] * inv;
      o1[e] = accO1[4 * rr + e] * inv;
    }
    *(f32x4*)(op + 8 * rr + 4 * h)      = o0;   // d-tile 0
    *(f32x4*)(op + 32 + 8 * rr + 4 * h) = o1;   // d-tile 1
  }
}

extern "C" void kernel_launch(void* const* d_in, const int* in_sizes, int n_in,
                              void* d_out, int out_size, void* d_ws, size_t ws_size,
                              hipStream_t stream) {
  const float* Q = (const float*)d_in[0];
  const float* K = (const float*)d_in[1];
  const float* V = (const float*)d_in[2];
  const int*   M = (const int*)d_in[3];
  float* Out = (float*)d_out;

  const size_t NE = (size_t)B_ * H_ * S_ * D_;              // 4194304
  _Float16* Kh  = (_Float16*)d_ws;                          // 8 MB
  _Float16* Vth = Kh + NE;                                  // 8 MB (transposed)
  unsigned long long* Mb = (unsigned long long*)(Vth + NE); // 1 MB

  prepass_k<<<2048, 256, 0, stream>>>(K, V, M, Kh, Vth, Mb);
  attn_fwd<<<NQT * BH_, 256, 0, stream>>>(Q, Kh, Vth, Mb, Out);
}

// Round 8
// 190.564 us; speedup vs baseline: 1.1414x; 1.0109x over previous
//
#include <hip/hip_runtime.h>

// ScaledDotProductAttention: B=2,H=16,S=2048,DK=64, fp32 in/out, int mask (0/1).
// R8 = R7 (32x32 MFMA, in-register P via permlane32_swap) + KV-SPLIT:
// 8-wave blocks; waves 0-3 do even kv tiles, 4-7 odd, same q rows; exact
// flash combine at the end. Quad-buffered staging [set][parity]. 16 waves/CU.

#define S_   2048
#define D_   64
#define H_   16
#define B_   2
#define BH_  32
#define KVB  64
#define NKV  (S_/KVB)      // 32
#define NRND (NKV/2)       // 16 rounds, one tile-pair each
#define QPB  128           // 4 q sub-tiles x 32 rows
#define NQT  (S_/QPB)      // 16

// softmax scale folded into K prepass, in log2 domain: 1/sqrt(64) * log2(e)
#define KSCALE 0.18033688f

typedef __attribute__((ext_vector_type(8)))  _Float16 f16x8;
typedef __attribute__((ext_vector_type(4)))  _Float16 f16x4;
typedef __attribute__((ext_vector_type(2)))  _Float16 f16x2;
typedef __attribute__((ext_vector_type(4)))  float    f32x4;
typedef __attribute__((ext_vector_type(16))) float    f32x16;
typedef __attribute__((ext_vector_type(4)))  unsigned u32x4;

static __device__ __forceinline__ void async16(const void* g, void* l) {
  __builtin_amdgcn_global_load_lds(
      (const __attribute__((address_space(1))) void*)g,
      (__attribute__((address_space(3))) void*)l, 16, 0, 0);
}

static __device__ __forceinline__ f16x2 pkrtz(float a, float b) {
  return __builtin_bit_cast(f16x2, __builtin_amdgcn_cvt_pkrtz(a, b));
}

// exchange a<->b across wave halves (lane<32 keeps a / gets partner's a ...)
static __device__ __forceinline__ void plswap(unsigned& a, unsigned& b, int h) {
#if __has_builtin(__builtin_amdgcn_permlane32_swap)
  auto r = __builtin_amdgcn_permlane32_swap(a, b, false, false);
  a = (unsigned)r[0];
  b = (unsigned)r[1];
#else
  unsigned sa = __shfl_xor(a, 32), sb = __shfl_xor(b, 32);
  unsigned na = h ? sb : a, nb = h ? b : sa;
  a = na; b = nb;
#endif
}

// ---------------- fused prepass (unchanged) ----------------
__global__ __launch_bounds__(256) void prepass_k(
    const float* __restrict__ K, const float* __restrict__ V,
    const int* __restrict__ M,
    _Float16* __restrict__ Kh, _Float16* __restrict__ Vth,
    unsigned long long* __restrict__ Mb) {
  __shared__ float tile[64][65];
  const int bidx = blockIdx.x;
  const int tid = threadIdx.x;
  if (bidx < 1024) {
    int st = bidx & 31;
    int bh = bidx >> 5;
    const float* src = V + ((size_t)bh * S_ + st * 64) * D_;
    int r = tid >> 2, cq = tid & 3;
#pragma unroll
    for (int j = 0; j < 4; ++j) {
      float4 v = ((const float4*)(src + (size_t)r * D_))[cq + 4 * j];
      int col = (cq + 4 * j) * 4;
      tile[r][col + 0] = v.x; tile[r][col + 1] = v.y;
      tile[r][col + 2] = v.z; tile[r][col + 3] = v.w;
    }
    __syncthreads();
    int d = tid >> 2, s = (tid & 3) * 16;
    _Float16 tmp[16];
#pragma unroll
    for (int j = 0; j < 16; ++j) tmp[j] = (_Float16)tile[s + j][d];
    _Float16* dstp = Vth + ((size_t)bh * D_ + d) * S_ + st * 64 + s;
    *(f16x8*)(dstp)     = *((f16x8*)tmp);
    *(f16x8*)(dstp + 8) = *((f16x8*)tmp + 1);
  } else if (bidx < 1536) {
    int idx = (bidx - 1024) * 256 + tid;
#pragma unroll
    for (int j = 0; j < 8; ++j) {
      int i = idx + j * 131072;
      float4 v = ((const float4*)K)[i];
      f16x4 o = {(_Float16)(v.x * KSCALE), (_Float16)(v.y * KSCALE),
                 (_Float16)(v.z * KSCALE), (_Float16)(v.w * KSCALE)};
      *(f16x4*)(Kh + 4 * (size_t)i) = o;
    }
  } else {
    int lane = tid & 63;
    int wb = (bidx - 1536) * 256 + (tid >> 6) * 64;
    for (int i = 0; i < 64; ++i) {
      int w = wb + i;
      int m = M[(size_t)w * 64 + lane];
      unsigned long long bal = __ballot(m != 0);
      if (lane == 0) Mb[w] = bal;
    }
  }
}

// ---------------- main attention ----------------
__global__ __launch_bounds__(512, 4) void attn_fwd(
    const float* __restrict__ Qf, const _Float16* __restrict__ Kh,
    const _Float16* __restrict__ Vth, const unsigned long long* __restrict__ Mb,
    float* __restrict__ Out) {
  __shared__ _Float16 Kt[2][2][KVB * D_];    // 32KB [set][kv-parity][row][d]
  __shared__ _Float16 Vt[2][2][D_ * KVB];    // 32KB [set][kv-parity][d][k]
  __shared__ unsigned long long MLUT[16];

  const int tid = threadIdx.x;
  const int lane = tid & 63;
  const int wid = tid >> 6;                  // 0..7
  const int p = wid & 3;                     // q sub-tile
  const int half = wid >> 2;                 // kv parity (0: even tiles, 1: odd)
  const int h = lane >> 5;
  const int c5 = lane & 31;
  const int c7 = c5 & 7;

  if (tid < 16) {
    unsigned w0 = ((tid & 1) ? 0x3C00u : 0u) | ((tid & 2) ? 0x3C000000u : 0u);
    unsigned w1 = ((tid & 4) ? 0x3C00u : 0u) | ((tid & 8) ? 0x3C000000u : 0u);
    MLUT[tid] = (unsigned long long)w0 | ((unsigned long long)w1 << 32);
  }

  int bid = blockIdx.x;
  bid = (bid & 7) * 64 + (bid >> 3);         // XCD swizzle, bijective (512 = 8*64)
  const int qt = bid & (NQT - 1);
  const int bh = bid >> 4;
  const int b = bh >> 4;                     // bh = b*16 + h

  const int q = qt * QPB + p * 32 + c5;      // this lane's q row

  // ---- Q fragments from fp32 global: qf[dc] = Q[q][16dc+8h .. +8) ----
  f16x8 qf[4];
  {
    const float* qp = Qf + ((size_t)bh * S_ + q) * D_ + 8 * h;
#pragma unroll
    for (int dc = 0; dc < 4; ++dc) {
      _Float16 t[8];
#pragma unroll
      for (int j = 0; j < 8; ++j) t[j] = (_Float16)qp[16 * dc + j];
      qf[dc] = *(f16x8*)t;
    }
  }

  f32x16 accO0, accO1;
#pragma unroll
  for (int e = 0; e < 16; ++e) { accO0[e] = 0.f; accO1[e] = 0.f; }
  float m_run = -INFINITY, l_run = 0.f;

  // staging: 512 threads cover one 64x64 f16 tile (64 rows x 8 granules)
  const int srow = tid >> 3, sgr = tid & 7;
  const int gs = (sgr ^ (srow & 7)) << 3;    // pre-swizzled source granule
  const _Float16* kp = Kh + (size_t)bh * S_ * D_ + (size_t)srow * D_ + gs;
  const _Float16* vp = Vth + (size_t)bh * D_ * S_ + (size_t)srow * S_ + gs;
  const int ldso = (tid & ~63) * 8;          // wave-uniform LDS base
  const unsigned long long* pmb = Mb + ((size_t)b * S_ + q) * NKV;
  const f16x2 one2 = {(_Float16)1.0f, (_Float16)1.0f};

#define STAGE1(set, par, t)                                          \
  {                                                                  \
    async16(kp + (size_t)(t) * (KVB * D_), &Kt[set][par][ldso]);     \
    async16(vp + (size_t)(t) * KVB,        &Vt[set][par][ldso]);     \
  }

  STAGE1(0, 0, 0);                           // prologue tile-pair {0,1} -> set 0
  STAGE1(0, 1, 1);

#pragma unroll 2
  for (int r = 0; r < NRND; ++r) {
    const int cur = r & 1;
    __syncthreads();                         // set[cur] staged for all waves
    unsigned long long mw = pmb[2 * r + half];
    if (r + 1 < NRND) {                      // stage next pair -> other set
      STAGE1(cur ^ 1, 0, 2 * r + 2);
      STAGE1(cur ^ 1, 1, 2 * r + 3);
    }

    const _Float16* Ktc = Kt[cur][half];
    const _Float16* Vtc = Vt[cur][half];

    // ---- QK^T: S^T = K*Q^T in two 32x32 tiles, chained over d ----
    f32x16 st0, st1;
#pragma unroll
    for (int e = 0; e < 16; ++e) { st0[e] = 0.f; st1[e] = 0.f; }
    __builtin_amdgcn_s_setprio(1);
#pragma unroll
    for (int dc = 0; dc < 4; ++dc) {
      int slot = (((2 * dc + h) ^ c7) << 3);
      f16x8 k0 = *(const f16x8*)(&Ktc[(c5)      * D_ + slot]);
      f16x8 k1 = *(const f16x8*)(&Ktc[(32 + c5) * D_ + slot]);
      st0 = __builtin_amdgcn_mfma_f32_32x32x16_f16(k0, qf[dc], st0, 0, 0, 0);
      st1 = __builtin_amdgcn_mfma_f32_32x32x16_f16(k1, qf[dc], st1, 0, 0, 0);
    }
    __builtin_amdgcn_s_setprio(0);
    // lane (h,c5) holds S[q][k = kt*32 + (e&3) + 8*(e>>2) + 4h], col q = c5

    // ---- online softmax (exp2 domain), row spans lanes {c5, c5+32} ----
    float pmax = -INFINITY;
#pragma unroll
    for (int e = 0; e < 16; ++e) {
      pmax = fmaxf(pmax, st0[e]);
      pmax = fmaxf(pmax, st1[e]);
    }
    pmax = fmaxf(pmax, __shfl_xor(pmax, 32));
    if (!__all(pmax - m_run <= 8.f)) {       // defer-max (T13)
      float mn = fmaxf(m_run, pmax);
      float cf = __builtin_amdgcn_exp2f(m_run - mn);
      l_run *= cf;
#pragma unroll
      for (int e = 0; e < 16; ++e) { accO0[e] *= cf; accO1[e] *= cf; }
      m_run = mn;
    }

    // ---- exp2 + mask (post-exp LUT) + f16 pack + row-sum ----
    float rs = 0.f;
    unsigned pkd[2][4][2];
#pragma unroll
    for (int kt = 0; kt < 2; ++kt) {
#pragma unroll
      for (int rr = 0; rr < 4; ++rr) {
        int n = 8 * kt + 2 * rr + h;
        unsigned nib = (unsigned)(mw >> (4 * n)) & 0xFu;
        unsigned long long lut = MLUT[nib];
        f16x2 m01 = __builtin_bit_cast(f16x2, (unsigned)lut);
        f16x2 m23 = __builtin_bit_cast(f16x2, (unsigned)(lut >> 32));
        float e0 = (kt ? st1[4 * rr + 0] : st0[4 * rr + 0]) - m_run;
        float e1 = (kt ? st1[4 * rr + 1] : st0[4 * rr + 1]) - m_run;
        float e2 = (kt ? st1[4 * rr + 2] : st0[4 * rr + 2]) - m_run;
        float e3 = (kt ? st1[4 * rr + 3] : st0[4 * rr + 3]) - m_run;
        f16x2 p0 = pkrtz(__builtin_amdgcn_exp2f(e0), __builtin_amdgcn_exp2f(e1)) * m01;
        f16x2 p1 = pkrtz(__builtin_amdgcn_exp2f(e2), __builtin_amdgcn_exp2f(e3)) * m23;
        rs = __builtin_amdgcn_fdot2(p0, one2, rs, false);
        rs = __builtin_amdgcn_fdot2(p1, one2, rs, false);
        pkd[kt][rr][0] = __builtin_bit_cast(unsigned, p0);
        pkd[kt][rr][1] = __builtin_bit_cast(unsigned, p1);
      }
    }
    rs += __shfl_xor(rs, 32);
    l_run += rs;

    // ---- P redistribution: half-wave chunk exchange -> B-operand frags ----
    f16x8 pfrag[4];
#pragma unroll
    for (int kc = 0; kc < 4; ++kc) {
      int jl = 2 * kc, jh = 2 * kc + 1;
      unsigned a0 = pkd[jl >> 2][jl & 3][0], a1 = pkd[jl >> 2][jl & 3][1];
      unsigned b0 = pkd[jh >> 2][jh & 3][0], b1 = pkd[jh >> 2][jh & 3][1];
      plswap(a0, b0, h);
      plswap(a1, b1, h);
      u32x4 fr = {a0, a1, b0, b1};
      pfrag[kc] = __builtin_bit_cast(f16x8, fr);
    }

    // ---- PV: O^T = V^T * P^T, two d-tiles, chained over k ----
    __builtin_amdgcn_s_setprio(1);
#pragma unroll
    for (int kc = 0; kc < 4; ++kc) {
      int slot = (((2 * kc + h) ^ c7) << 3);
      f16x8 v0 = *(const f16x8*)(&Vtc[(c5)      * KVB + slot]);
      f16x8 v1 = *(const f16x8*)(&Vtc[(32 + c5) * KVB + slot]);
      accO0 = __builtin_amdgcn_mfma_f32_32x32x16_f16(v0, pfrag[kc], accO0, 0, 0, 0);
      accO1 = __builtin_amdgcn_mfma_f32_32x32x16_f16(v1, pfrag[kc], accO1, 0, 0, 0);
    }
    __builtin_amdgcn_s_setprio(0);
  }

  // ---- pair combine (exact): waves 4-7 dump, waves 0-3 merge + store ----
  __syncthreads();                           // all LDS tile reads done
  {
    float* cbA = (float*)&Kt[0][0][0];       // [4][64][17]: accO0 + m
    float* cbB = (float*)&Vt[0][0][0];       // [4][64][17]: accO1 + l
    if (half) {
      float* da = cbA + (p * 64 + lane) * 17;
      float* db = cbB + (p * 64 + lane) * 17;
#pragma unroll
      for (int e = 0; e < 16; ++e) { da[e] = accO0[e]; db[e] = accO1[e]; }
      da[16] = m_run; db[16] = l_run;
    }
    __syncthreads();
    if (!half) {
      const float* sa = cbA + (p * 64 + lane) * 17;
      const float* sb = cbB + (p * 64 + lane) * 17;
      float m_b = sa[16], l_b = sb[16];
      float m = fmaxf(m_run, m_b);
      float ca  = __builtin_amdgcn_exp2f(m_run - m);
      float cb2 = __builtin_amdgcn_exp2f(m_b - m);
      float inv = 1.0f / (l_run * ca + l_b * cb2);
      float* op = Out + ((size_t)bh * S_ + q) * D_;
#pragma unroll
      for (int rr = 0; rr < 4; ++rr) {
        f32x4 o0, o1;
#pragma unroll
        for (int e = 0; e < 4; ++e) {
          o0[e] = (accO0[4 * rr + e] * ca + sa[4 * rr + e] * cb2) * inv;
          o1[e] = (accO1[4 * rr + e] * ca + sb[4 * rr + e] * cb2) * inv;
        }
        *(f32x4*)(op + 8 * rr + 4 * h)      = o0;   // d-tile 0
        *(f32x4*)(op + 32 + 8 * rr + 4 * h) = o1;   // d-tile 1
      }
    }
  }
}

extern "C" void kernel_launch(void* const* d_in, const int* in_sizes, int n_in,
                              void* d_out, int out_size, void* d_ws, size_t ws_size,
                              hipStream_t stream) {
  const float* Q = (const float*)d_in[0];
  const float* K = (const float*)d_in[1];
  const float* V = (const float*)d_in[2];
  const int*   M = (const int*)d_in[3];
  float* Out = (float*)d_out;

  const size_t NE = (size_t)B_ * H_ * S_ * D_;              // 4194304
  _Float16* Kh  = (_Float16*)d_ws;                          // 8 MB
  _Float16* Vth = Kh + NE;                                  // 8 MB (transposed)
  unsigned long long* Mb = (unsigned long long*)(Vth + NE); // 1 MB

  prepass_k<<<2048, 256, 0, stream>>>(K, V, M, Kh, Vth, Mb);
  attn_fwd<<<NQT * BH_, 512, 0, stream>>>(Q, Kh, Vth, Mb, Out);
}